// Round 2
// baseline (2146.795 us; speedup 1.0000x reference)
//
#include <hip/hip_runtime.h>
#include <cstdint>
#include <cstddef>

#define NN   100000
#define EE   1600000
#define INF_ 128
#define HIDF 64
#define NH   3
#define FEAT 192   // NH*HIDF
#define OUTF 16
#define NEG  0.2f

// ---------------- CSR build ----------------

__global__ void hist_kernel(const int* __restrict__ dst, int* __restrict__ counts) {
    int e = blockIdx.x * 256 + threadIdx.x;
    if (e < EE) atomicAdd(&counts[dst[e]], 1);
}

__global__ __launch_bounds__(1024) void scan_kernel(const int* __restrict__ counts,
                                                    int* __restrict__ row_ptr,
                                                    int* __restrict__ cursor) {
    __shared__ int sd[1024];
    int t = threadIdx.x;
    const int CH = (NN + 1023) / 1024;
    int b = t * CH, e = min(b + CH, NN);
    int s = 0;
    for (int i = b; i < e; ++i) s += counts[i];
    sd[t] = s;
    __syncthreads();
    for (int off = 1; off < 1024; off <<= 1) {
        int v = (t >= off) ? sd[t - off] : 0;
        __syncthreads();
        sd[t] += v;
        __syncthreads();
    }
    int run = (t == 0) ? 0 : sd[t - 1];
    for (int i = b; i < e; ++i) {
        row_ptr[i] = run;
        cursor[i]  = run;
        run += counts[i];
    }
    if (t == 1023) row_ptr[NN] = run;   // == EE
}

__global__ void scatter_kernel(const int* __restrict__ src, const int* __restrict__ dst,
                               int* __restrict__ cursor, int* __restrict__ ssrc) {
    int e = blockIdx.x * 256 + threadIdx.x;
    if (e < EE) {
        int p = atomicAdd(&cursor[dst[e]], 1);
        ssrc[p] = src[e];
    }
}

// ---------------- GEMM: one (or few) rows per block, A staged in LDS ----------------

template <int K, int M, int ROWS, bool BIAS, bool RELU>
__global__ void rowgemm_kernel(const float* __restrict__ A, const float* __restrict__ W,
                               const float* __restrict__ bias, float* __restrict__ C) {
    __shared__ float a[ROWS][K];
    const int BT = M * ROWS;
    int r0 = blockIdx.x * ROWS;
    for (int i = threadIdx.x; i < ROWS * K; i += BT) {
        int rr = i / K, kk = i - rr * K;
        int row = r0 + rr;
        a[rr][kk] = (row < NN) ? A[(size_t)row * K + kk] : 0.f;
    }
    __syncthreads();
    int rr = threadIdx.x / M, c = threadIdx.x - rr * M;
    int row = r0 + rr;
    if (row >= NN) return;
    float acc = 0.f;
#pragma unroll
    for (int k = 0; k < K; ++k) acc += a[rr][k] * W[k * M + c];
    if (BIAS) acc += bias[c];
    if (RELU) acc = fmaxf(acc, 0.f);
    C[(size_t)row * M + c] = acc;
}

// ---------------- el/er: per (node, head) dot products ----------------

__global__ void eler_kernel(const float* __restrict__ feat, const float* __restrict__ al,
                            const float* __restrict__ ar, float* __restrict__ el,
                            float* __restrict__ er) {
    int idx = blockIdx.x * 256 + threadIdx.x;
    if (idx >= NN * NH) return;
    int n = idx / NH, h = idx - n * NH;
    const float* fr = feat + (size_t)n * FEAT + h * HIDF;
    const float* A  = al + h * HIDF;
    const float* B  = ar + h * HIDF;
    float sl = 0.f, sr = 0.f;
#pragma unroll
    for (int d = 0; d < HIDF; ++d) {
        float f = fr[d];
        sl += f * A[d];
        sr += f * B[d];
    }
    el[idx] = sl;
    er[idx] = sr;
}

// ---------------- aggregation: one wave per dst node ----------------
// pass 1: per-head max over incoming edges; pass 2: exp-sum + weighted feat gather.
// lane l owns output dims {l, 64+l, 128+l} (head 0,1,2, dim l).

__global__ __launch_bounds__(256) void aggregate_kernel(
    const int* __restrict__ row_ptr, const int* __restrict__ ssrc,
    const float* __restrict__ feat, const float* __restrict__ el,
    const float* __restrict__ er, const float* __restrict__ bias,
    float* __restrict__ out) {
    int w = blockIdx.x * 4 + (threadIdx.x >> 6);
    if (w >= NN) return;
    int lane = threadIdx.x & 63;
    int beg = row_ptr[w], end = row_ptr[w + 1];
    float er0 = er[w * 3 + 0], er1 = er[w * 3 + 1], er2 = er[w * 3 + 2];

    float m0 = -3.4e38f, m1 = -3.4e38f, m2 = -3.4e38f;
    for (int e = beg; e < end; ++e) {
        int s = ssrc[e];
        float a0 = el[s * 3 + 0] + er0; a0 = a0 > 0.f ? a0 : NEG * a0;
        float a1 = el[s * 3 + 1] + er1; a1 = a1 > 0.f ? a1 : NEG * a1;
        float a2 = el[s * 3 + 2] + er2; a2 = a2 > 0.f ? a2 : NEG * a2;
        m0 = fmaxf(m0, a0); m1 = fmaxf(m1, a1); m2 = fmaxf(m2, a2);
    }

    float s0 = 0.f, s1 = 0.f, s2 = 0.f;
    float acc0 = 0.f, acc1 = 0.f, acc2 = 0.f;
    for (int e = beg; e < end; ++e) {
        int s = ssrc[e];
        float a0 = el[s * 3 + 0] + er0; a0 = a0 > 0.f ? a0 : NEG * a0;
        float a1 = el[s * 3 + 1] + er1; a1 = a1 > 0.f ? a1 : NEG * a1;
        float a2 = el[s * 3 + 2] + er2; a2 = a2 > 0.f ? a2 : NEG * a2;
        float w0 = __expf(a0 - m0), w1 = __expf(a1 - m1), w2 = __expf(a2 - m2);
        s0 += w0; s1 += w1; s2 += w2;
        const float* fr = feat + (size_t)s * FEAT;
        acc0 += w0 * fr[lane];
        acc1 += w1 * fr[64 + lane];
        acc2 += w2 * fr[128 + lane];
    }

    float r0, r1, r2;
    if (end > beg) { r0 = acc0 / s0; r1 = acc1 / s1; r2 = acc2 / s2; }
    else           { r0 = r1 = r2 = 0.f; }
    r0 += bias[lane]; r1 += bias[64 + lane]; r2 += bias[128 + lane];
    out[(size_t)w * FEAT + lane]       = fmaxf(r0, 0.f);
    out[(size_t)w * FEAT + 64 + lane]  = fmaxf(r1, 0.f);
    out[(size_t)w * FEAT + 128 + lane] = fmaxf(r2, 0.f);
}

// ---------------- launch ----------------

extern "C" void kernel_launch(void* const* d_in, const int* in_sizes, int n_in,
                              void* d_out, int out_size, void* d_ws, size_t ws_size,
                              hipStream_t stream) {
    const float* features = (const float*)d_in[0];
    const int*   src      = (const int*)d_in[1];
    const int*   dst      = (const int*)d_in[2];
    const float* W1  = (const float*)d_in[3];
    const float* al1 = (const float*)d_in[4];
    const float* ar1 = (const float*)d_in[5];
    const float* b1  = (const float*)d_in[6];
    const float* W2  = (const float*)d_in[7];
    const float* al2 = (const float*)d_in[8];
    const float* ar2 = (const float*)d_in[9];
    const float* b2  = (const float*)d_in[10];
    const float* w3  = (const float*)d_in[11];
    const float* b3  = (const float*)d_in[12];
    const float* w4  = (const float*)d_in[13];
    const float* b4  = (const float*)d_in[14];
    float* out = (float*)d_out;

    char* p = (char*)d_ws;
    float* feat = (float*)p; p += (size_t)NN * FEAT * 4;
    float* x    = (float*)p; p += (size_t)NN * FEAT * 4;
    float* el   = (float*)p; p += (size_t)NN * NH * 4;
    float* er   = (float*)p; p += (size_t)NN * NH * 4;
    int* counts  = (int*)p;  p += (size_t)NN * 4;
    int* row_ptr = (int*)p;  p += (size_t)(NN + 1) * 4;
    int* cursor  = (int*)p;  p += (size_t)NN * 4;
    int* ssrc    = (int*)p;  p += (size_t)EE * 4;

    // CSR by dst (same for both layers)
    hipMemsetAsync(counts, 0, (size_t)NN * 4, stream);
    hist_kernel<<<(EE + 255) / 256, 256, 0, stream>>>(dst, counts);
    scan_kernel<<<1, 1024, 0, stream>>>(counts, row_ptr, cursor);
    scatter_kernel<<<(EE + 255) / 256, 256, 0, stream>>>(src, dst, cursor, ssrc);

    // ---- layer 1 ----
    rowgemm_kernel<INF_, FEAT, 1, false, false><<<NN, FEAT, 0, stream>>>(features, W1, nullptr, feat);
    eler_kernel<<<(NN * NH + 255) / 256, 256, 0, stream>>>(feat, al1, ar1, el, er);
    aggregate_kernel<<<(NN + 3) / 4, 256, 0, stream>>>(row_ptr, ssrc, feat, el, er, b1, x);

    // ---- layer 2 ----
    rowgemm_kernel<FEAT, FEAT, 1, false, false><<<NN, FEAT, 0, stream>>>(x, W2, nullptr, feat);
    eler_kernel<<<(NN * NH + 255) / 256, 256, 0, stream>>>(feat, al2, ar2, el, er);
    aggregate_kernel<<<(NN + 3) / 4, 256, 0, stream>>>(row_ptr, ssrc, feat, el, er, b2, x);

    // ---- MLP head ---- (reuse feat as hidden buffer)
    rowgemm_kernel<FEAT, HIDF, 4, true, true><<<NN / 4, 256, 0, stream>>>(x, w3, b3, feat);
    rowgemm_kernel<HIDF, OUTF, 16, true, false><<<NN / 16, 256, 0, stream>>>(feat, w4, b4, out);
}

// Round 3
// 1206.589 us; speedup vs baseline: 1.7792x; 1.7792x over previous
//
#include <hip/hip_runtime.h>
#include <cstdint>
#include <cstddef>

#define NN   100000
#define EE   1600000
#define INF_ 128
#define HIDF 64
#define NH   3
#define FEAT 192   // NH*HIDF
#define OUTF 16
#define NEG  0.2f

// ---------------- CSR build ----------------

__global__ void hist_kernel(const int* __restrict__ dst, int* __restrict__ counts) {
    int e = blockIdx.x * 256 + threadIdx.x;
    if (e < EE) atomicAdd(&counts[dst[e]], 1);
}

__global__ __launch_bounds__(1024) void scan_kernel(const int* __restrict__ counts,
                                                    int* __restrict__ row_ptr,
                                                    int* __restrict__ cursor) {
    __shared__ int sd[1024];
    int t = threadIdx.x;
    const int CH = (NN + 1023) / 1024;
    int b = t * CH, e = min(b + CH, NN);
    int s = 0;
    for (int i = b; i < e; ++i) s += counts[i];
    sd[t] = s;
    __syncthreads();
    for (int off = 1; off < 1024; off <<= 1) {
        int v = (t >= off) ? sd[t - off] : 0;
        __syncthreads();
        sd[t] += v;
        __syncthreads();
    }
    int run = (t == 0) ? 0 : sd[t - 1];
    for (int i = b; i < e; ++i) {
        row_ptr[i] = run;
        cursor[i]  = run;
        run += counts[i];
    }
    if (t == 1023) row_ptr[NN] = run;   // == EE
}

__global__ void scatter_kernel(const int* __restrict__ src, const int* __restrict__ dst,
                               int* __restrict__ cursor, int* __restrict__ ssrc) {
    int e = blockIdx.x * 256 + threadIdx.x;
    if (e < EE) {
        int p = atomicAdd(&cursor[dst[e]], 1);
        ssrc[p] = src[e];
    }
}

// ---------------- tiled fp32 GEMM: 64x64 block tile, BK=32, 4x4 per thread ----------------

template <int K, int N, bool BIAS, bool RELU>
__global__ __launch_bounds__(256) void gemm64_kernel(const float* __restrict__ A,
                                                     const float* __restrict__ B,
                                                     const float* __restrict__ bias,
                                                     float* __restrict__ C) {
    __shared__ float As[32][64];   // [k][m] (transposed)
    __shared__ float Bs[32][64];   // [k][n]
    const int m0 = blockIdx.x * 64;
    const int n0 = blockIdx.y * 64;
    const int t  = threadIdx.x;
    const int tr = t >> 4;         // 0..15 -> output rows tr*4..tr*4+3
    const int tc = t & 15;         // 0..15 -> output cols tc*4..tc*4+3

    float acc[4][4] = {};

    for (int kt = 0; kt < K; kt += 32) {
        // A tile: 64 rows x 32 cols, transpose into As[k][m]
        {
            int f = t;                       // 512 float4 / 256 threads = 2 each
#pragma unroll
            for (int it = 0; it < 2; ++it, f += 256) {
                int row = f >> 3, c4 = (f & 7) * 4;
                float4 v = make_float4(0.f, 0.f, 0.f, 0.f);
                int gr = m0 + row;
                if (gr < NN) v = *(const float4*)(A + (size_t)gr * K + kt + c4);
                As[c4 + 0][row] = v.x;
                As[c4 + 1][row] = v.y;
                As[c4 + 2][row] = v.z;
                As[c4 + 3][row] = v.w;
            }
        }
        // B tile: 32 rows x 64 cols
        {
            int f = t;
#pragma unroll
            for (int it = 0; it < 2; ++it, f += 256) {
                int row = f >> 4, c4 = (f & 15) * 4;
                *(float4*)&Bs[row][c4] = *(const float4*)(B + (size_t)(kt + row) * N + n0 + c4);
            }
        }
        __syncthreads();
#pragma unroll
        for (int k = 0; k < 32; ++k) {
            float4 a = *(const float4*)&As[k][tr * 4];
            float4 b = *(const float4*)&Bs[k][tc * 4];
            acc[0][0] += a.x * b.x; acc[0][1] += a.x * b.y; acc[0][2] += a.x * b.z; acc[0][3] += a.x * b.w;
            acc[1][0] += a.y * b.x; acc[1][1] += a.y * b.y; acc[1][2] += a.y * b.z; acc[1][3] += a.y * b.w;
            acc[2][0] += a.z * b.x; acc[2][1] += a.z * b.y; acc[2][2] += a.z * b.z; acc[2][3] += a.z * b.w;
            acc[3][0] += a.w * b.x; acc[3][1] += a.w * b.y; acc[3][2] += a.w * b.z; acc[3][3] += a.w * b.w;
        }
        __syncthreads();
    }

    float4 bv = make_float4(0.f, 0.f, 0.f, 0.f);
    if (BIAS) bv = *(const float4*)(bias + n0 + tc * 4);
#pragma unroll
    for (int i = 0; i < 4; ++i) {
        int row = m0 + tr * 4 + i;
        if (row >= NN) continue;
        float4 r;
        r.x = acc[i][0]; r.y = acc[i][1]; r.z = acc[i][2]; r.w = acc[i][3];
        if (BIAS) { r.x += bv.x; r.y += bv.y; r.z += bv.z; r.w += bv.w; }
        if (RELU) {
            r.x = fmaxf(r.x, 0.f); r.y = fmaxf(r.y, 0.f);
            r.z = fmaxf(r.z, 0.f); r.w = fmaxf(r.w, 0.f);
        }
        *(float4*)(C + (size_t)row * N + n0 + tc * 4) = r;
    }
}

// ---------------- small GEMM for the 64->16 head ----------------

template <int K, int M, int ROWS, bool BIAS, bool RELU>
__global__ void rowgemm_kernel(const float* __restrict__ A, const float* __restrict__ W,
                               const float* __restrict__ bias, float* __restrict__ C) {
    __shared__ float a[ROWS][K];
    const int BT = M * ROWS;
    int r0 = blockIdx.x * ROWS;
    for (int i = threadIdx.x; i < ROWS * K; i += BT) {
        int rr = i / K, kk = i - rr * K;
        int row = r0 + rr;
        a[rr][kk] = (row < NN) ? A[(size_t)row * K + kk] : 0.f;
    }
    __syncthreads();
    int rr = threadIdx.x / M, c = threadIdx.x - rr * M;
    int row = r0 + rr;
    if (row >= NN) return;
    float acc = 0.f;
#pragma unroll
    for (int k = 0; k < K; ++k) acc += a[rr][k] * W[k * M + c];
    if (BIAS) acc += bias[c];
    if (RELU) acc = fmaxf(acc, 0.f);
    C[(size_t)row * M + c] = acc;
}

// ---------------- el/er: per (node, head) dot products, float4 ----------------

__global__ void eler_kernel(const float* __restrict__ feat, const float* __restrict__ al,
                            const float* __restrict__ ar, float* __restrict__ el,
                            float* __restrict__ er) {
    int idx = blockIdx.x * 256 + threadIdx.x;
    if (idx >= NN * NH) return;
    int n = idx / NH, h = idx - n * NH;
    const float* fr = feat + (size_t)n * FEAT + h * HIDF;
    const float* A  = al + h * HIDF;
    const float* B  = ar + h * HIDF;
    float sl = 0.f, sr = 0.f;
#pragma unroll
    for (int d = 0; d < HIDF; d += 4) {
        float4 f = *(const float4*)(fr + d);
        float4 va = *(const float4*)(A + d);
        float4 vb = *(const float4*)(B + d);
        sl += f.x * va.x + f.y * va.y + f.z * va.z + f.w * va.w;
        sr += f.x * vb.x + f.y * vb.y + f.z * vb.z + f.w * vb.w;
    }
    el[idx] = sl;
    er[idx] = sr;
}

// ---------------- aggregation: one wave per dst node, single pass ----------------
// softmax is shift-invariant; |e| <= |el|+|er| is small (~10), so exp(e) is fp32-safe
// without the max-subtraction pass. lane l owns output dims {l, 64+l, 128+l}.

__global__ __launch_bounds__(256) void aggregate_kernel(
    const int* __restrict__ row_ptr, const int* __restrict__ ssrc,
    const float* __restrict__ feat, const float* __restrict__ el,
    const float* __restrict__ er, const float* __restrict__ bias,
    float* __restrict__ out) {
    int w = blockIdx.x * 4 + (threadIdx.x >> 6);
    if (w >= NN) return;
    int lane = threadIdx.x & 63;
    int beg = row_ptr[w], end = row_ptr[w + 1];
    float er0 = er[w * 3 + 0], er1 = er[w * 3 + 1], er2 = er[w * 3 + 2];

    float s0 = 0.f, s1 = 0.f, s2 = 0.f;
    float acc0 = 0.f, acc1 = 0.f, acc2 = 0.f;
    for (int e = beg; e < end; ++e) {
        int s = ssrc[e];
        float a0 = el[s * 3 + 0] + er0; a0 = a0 > 0.f ? a0 : NEG * a0;
        float a1 = el[s * 3 + 1] + er1; a1 = a1 > 0.f ? a1 : NEG * a1;
        float a2 = el[s * 3 + 2] + er2; a2 = a2 > 0.f ? a2 : NEG * a2;
        float w0 = __expf(a0), w1 = __expf(a1), w2 = __expf(a2);
        s0 += w0; s1 += w1; s2 += w2;
        const float* fr = feat + (size_t)s * FEAT;
        acc0 += w0 * fr[lane];
        acc1 += w1 * fr[64 + lane];
        acc2 += w2 * fr[128 + lane];
    }

    float r0, r1, r2;
    if (end > beg) { r0 = acc0 / s0; r1 = acc1 / s1; r2 = acc2 / s2; }
    else           { r0 = r1 = r2 = 0.f; }
    r0 += bias[lane]; r1 += bias[64 + lane]; r2 += bias[128 + lane];
    out[(size_t)w * FEAT + lane]       = fmaxf(r0, 0.f);
    out[(size_t)w * FEAT + 64 + lane]  = fmaxf(r1, 0.f);
    out[(size_t)w * FEAT + 128 + lane] = fmaxf(r2, 0.f);
}

// ---------------- launch ----------------

extern "C" void kernel_launch(void* const* d_in, const int* in_sizes, int n_in,
                              void* d_out, int out_size, void* d_ws, size_t ws_size,
                              hipStream_t stream) {
    const float* features = (const float*)d_in[0];
    const int*   src      = (const int*)d_in[1];
    const int*   dst      = (const int*)d_in[2];
    const float* W1  = (const float*)d_in[3];
    const float* al1 = (const float*)d_in[4];
    const float* ar1 = (const float*)d_in[5];
    const float* b1  = (const float*)d_in[6];
    const float* W2  = (const float*)d_in[7];
    const float* al2 = (const float*)d_in[8];
    const float* ar2 = (const float*)d_in[9];
    const float* b2  = (const float*)d_in[10];
    const float* w3  = (const float*)d_in[11];
    const float* b3  = (const float*)d_in[12];
    const float* w4  = (const float*)d_in[13];
    const float* b4  = (const float*)d_in[14];
    float* out = (float*)d_out;

    char* p = (char*)d_ws;
    float* feat = (float*)p; p += (size_t)NN * FEAT * 4;
    float* x    = (float*)p; p += (size_t)NN * FEAT * 4;
    float* el   = (float*)p; p += (size_t)NN * NH * 4;
    float* er   = (float*)p; p += (size_t)NN * NH * 4;
    int* counts  = (int*)p;  p += (size_t)NN * 4;
    int* row_ptr = (int*)p;  p += (size_t)(NN + 1) * 4;
    int* cursor  = (int*)p;  p += (size_t)NN * 4;
    int* ssrc    = (int*)p;  p += (size_t)EE * 4;

    const int GM = (NN + 63) / 64;   // 1563

    // CSR by dst (same for both layers)
    hipMemsetAsync(counts, 0, (size_t)NN * 4, stream);
    hist_kernel<<<(EE + 255) / 256, 256, 0, stream>>>(dst, counts);
    scan_kernel<<<1, 1024, 0, stream>>>(counts, row_ptr, cursor);
    scatter_kernel<<<(EE + 255) / 256, 256, 0, stream>>>(src, dst, cursor, ssrc);

    // ---- layer 1 ----
    gemm64_kernel<INF_, FEAT, false, false><<<dim3(GM, FEAT / 64), 256, 0, stream>>>(features, W1, nullptr, feat);
    eler_kernel<<<(NN * NH + 255) / 256, 256, 0, stream>>>(feat, al1, ar1, el, er);
    aggregate_kernel<<<(NN + 3) / 4, 256, 0, stream>>>(row_ptr, ssrc, feat, el, er, b1, x);

    // ---- layer 2 ----
    gemm64_kernel<FEAT, FEAT, false, false><<<dim3(GM, FEAT / 64), 256, 0, stream>>>(x, W2, nullptr, feat);
    eler_kernel<<<(NN * NH + 255) / 256, 256, 0, stream>>>(feat, al2, ar2, el, er);
    aggregate_kernel<<<(NN + 3) / 4, 256, 0, stream>>>(row_ptr, ssrc, feat, el, er, b2, x);

    // ---- MLP head ---- (reuse feat as hidden buffer)
    gemm64_kernel<FEAT, HIDF, true, true><<<dim3(GM, 1), 256, 0, stream>>>(x, w3, b3, feat);
    rowgemm_kernel<HIDF, OUTF, 16, true, false><<<NN / 16, 256, 0, stream>>>(feat, w4, b4, out);
}

// Round 4
// 944.660 us; speedup vs baseline: 2.2726x; 1.2773x over previous
//
#include <hip/hip_runtime.h>
#include <cstdint>
#include <cstddef>

#define NN   100000
#define EE   1600000
#define INF_ 128
#define HIDF 64
#define NH   3
#define FEAT 192   // NH*HIDF
#define OUTF 16
#define NEG  0.2f

#define NI4  25000   // NN/4
#define NB   98      // ceil(NN/1024)

// ---------------- CSR build ----------------

__global__ void hist_kernel(const int* __restrict__ dst, int* __restrict__ counts) {
    int e = blockIdx.x * 256 + threadIdx.x;
    if (e < EE) atomicAdd(&counts[dst[e]], 1);
}

// per-block (1024 ints) reduce -> bsum[b]
__global__ __launch_bounds__(256) void blocksum_kernel(const int* __restrict__ counts,
                                                       int* __restrict__ bsum) {
    int t = threadIdx.x;
    int idx4 = blockIdx.x * 256 + t;
    int s = 0;
    if (idx4 < NI4) {
        int4 v = ((const int4*)counts)[idx4];
        s = v.x + v.y + v.z + v.w;
    }
    __shared__ int sd[4];
    for (int o = 32; o; o >>= 1) s += __shfl_down(s, o, 64);
    if ((t & 63) == 0) sd[t >> 6] = s;
    __syncthreads();
    if (t == 0) bsum[blockIdx.x] = sd[0] + sd[1] + sd[2] + sd[3];
}

// exclusive scan of the 98 block sums (in place)
__global__ __launch_bounds__(128) void scanb_kernel(int* __restrict__ bsum) {
    __shared__ int sd[128];
    int t = threadIdx.x;
    int v = (t < NB) ? bsum[t] : 0;
    sd[t] = v;
    __syncthreads();
    for (int o = 1; o < 128; o <<= 1) {
        int u = (t >= o) ? sd[t - o] : 0;
        __syncthreads();
        sd[t] += u;
        __syncthreads();
    }
    if (t < NB) bsum[t] = sd[t] - v;   // exclusive
}

// per-block scan of counts + block offset -> row_ptr, cursor
__global__ __launch_bounds__(256) void scanfinal_kernel(const int* __restrict__ counts,
                                                        const int* __restrict__ bsum,
                                                        int* __restrict__ row_ptr,
                                                        int* __restrict__ cursor) {
    __shared__ int sd[256];
    int t = threadIdx.x;
    int idx4 = blockIdx.x * 256 + t;
    int4 v = make_int4(0, 0, 0, 0);
    if (idx4 < NI4) v = ((const int4*)counts)[idx4];
    int s = v.x + v.y + v.z + v.w;
    sd[t] = s;
    __syncthreads();
    for (int o = 1; o < 256; o <<= 1) {
        int u = (t >= o) ? sd[t - o] : 0;
        __syncthreads();
        sd[t] += u;
        __syncthreads();
    }
    int base = bsum[blockIdx.x] + sd[t] - s;   // exclusive prefix of element 4*idx4
    if (idx4 < NI4) {
        int4 r;
        r.x = base;
        r.y = base + v.x;
        r.z = base + v.x + v.y;
        r.w = base + v.x + v.y + v.z;
        ((int4*)row_ptr)[idx4] = r;
        ((int4*)cursor)[idx4]  = r;
    }
    if (blockIdx.x == 0 && t == 0) row_ptr[NN] = EE;
}

__global__ void scatter_kernel(const int* __restrict__ src, const int* __restrict__ dst,
                               int* __restrict__ cursor, int* __restrict__ ssrc) {
    int e = blockIdx.x * 256 + threadIdx.x;
    if (e < EE) {
        int p = atomicAdd(&cursor[dst[e]], 1);
        ssrc[p] = src[e];
    }
}

// ---------------- tiled fp32 GEMM: 64x64 block tile, BK=32, 4x4 per thread ----------------
// ELER: blockIdx.y == head h (N=192, 64 cols per head); fuse el/er dot products.

template <int K, int N, bool BIAS, bool RELU, bool ELER>
__global__ __launch_bounds__(256) void gemm64_kernel(const float* __restrict__ A,
                                                     const float* __restrict__ B,
                                                     const float* __restrict__ bias,
                                                     float* __restrict__ C,
                                                     const float* __restrict__ al,
                                                     const float* __restrict__ ar,
                                                     float* __restrict__ el,
                                                     float* __restrict__ er) {
    __shared__ float As[32][64];   // [k][m] (transposed)
    __shared__ float Bs[32][64];   // [k][n]
    const int m0 = blockIdx.x * 64;
    const int n0 = blockIdx.y * 64;
    const int t  = threadIdx.x;
    const int tr = t >> 4;         // 0..15 -> output rows tr*4..tr*4+3
    const int tc = t & 15;         // 0..15 -> output cols tc*4..tc*4+3

    float acc[4][4] = {};

    for (int kt = 0; kt < K; kt += 32) {
        {
            int f = t;                       // 512 float4 / 256 threads = 2 each
#pragma unroll
            for (int it = 0; it < 2; ++it, f += 256) {
                int row = f >> 3, c4 = (f & 7) * 4;
                float4 v = make_float4(0.f, 0.f, 0.f, 0.f);
                int gr = m0 + row;
                if (gr < NN) v = *(const float4*)(A + (size_t)gr * K + kt + c4);
                As[c4 + 0][row] = v.x;
                As[c4 + 1][row] = v.y;
                As[c4 + 2][row] = v.z;
                As[c4 + 3][row] = v.w;
            }
        }
        {
            int f = t;
#pragma unroll
            for (int it = 0; it < 2; ++it, f += 256) {
                int row = f >> 4, c4 = (f & 15) * 4;
                *(float4*)&Bs[row][c4] = *(const float4*)(B + (size_t)(kt + row) * N + n0 + c4);
            }
        }
        __syncthreads();
#pragma unroll
        for (int k = 0; k < 32; ++k) {
            float4 a = *(const float4*)&As[k][tr * 4];
            float4 b = *(const float4*)&Bs[k][tc * 4];
            acc[0][0] += a.x * b.x; acc[0][1] += a.x * b.y; acc[0][2] += a.x * b.z; acc[0][3] += a.x * b.w;
            acc[1][0] += a.y * b.x; acc[1][1] += a.y * b.y; acc[1][2] += a.y * b.z; acc[1][3] += a.y * b.w;
            acc[2][0] += a.z * b.x; acc[2][1] += a.z * b.y; acc[2][2] += a.z * b.z; acc[2][3] += a.z * b.w;
            acc[3][0] += a.w * b.x; acc[3][1] += a.w * b.y; acc[3][2] += a.w * b.z; acc[3][3] += a.w * b.w;
        }
        __syncthreads();
    }

    float4 bv = make_float4(0.f, 0.f, 0.f, 0.f);
    if (BIAS) bv = *(const float4*)(bias + n0 + tc * 4);
#pragma unroll
    for (int i = 0; i < 4; ++i) {
        int row = m0 + tr * 4 + i;
        if (row >= NN) continue;
        float4 r;
        r.x = acc[i][0]; r.y = acc[i][1]; r.z = acc[i][2]; r.w = acc[i][3];
        if (BIAS) { r.x += bv.x; r.y += bv.y; r.z += bv.z; r.w += bv.w; }
        if (RELU) {
            r.x = fmaxf(r.x, 0.f); r.y = fmaxf(r.y, 0.f);
            r.z = fmaxf(r.z, 0.f); r.w = fmaxf(r.w, 0.f);
        }
        *(float4*)(C + (size_t)row * N + n0 + tc * 4) = r;
    }

    if (ELER) {
        const int h = blockIdx.y;
        float4 va = *(const float4*)(al + h * HIDF + tc * 4);
        float4 vb = *(const float4*)(ar + h * HIDF + tc * 4);
#pragma unroll
        for (int i = 0; i < 4; ++i) {
            float pl = acc[i][0] * va.x + acc[i][1] * va.y + acc[i][2] * va.z + acc[i][3] * va.w;
            float pr = acc[i][0] * vb.x + acc[i][1] * vb.y + acc[i][2] * vb.z + acc[i][3] * vb.w;
#pragma unroll
            for (int o = 1; o < 16; o <<= 1) {
                pl += __shfl_xor(pl, o, 16);
                pr += __shfl_xor(pr, o, 16);
            }
            int row = m0 + tr * 4 + i;
            if (tc == 0 && row < NN) {
                el[row * NH + h] = pl;
                er[row * NH + h] = pr;
            }
        }
    }
}

// ---------------- small GEMM for the 64->16 head ----------------

template <int K, int M, int ROWS, bool BIAS, bool RELU>
__global__ void rowgemm_kernel(const float* __restrict__ A, const float* __restrict__ W,
                               const float* __restrict__ bias, float* __restrict__ C) {
    __shared__ float a[ROWS][K];
    const int BT = M * ROWS;
    int r0 = blockIdx.x * ROWS;
    for (int i = threadIdx.x; i < ROWS * K; i += BT) {
        int rr = i / K, kk = i - rr * K;
        int row = r0 + rr;
        a[rr][kk] = (row < NN) ? A[(size_t)row * K + kk] : 0.f;
    }
    __syncthreads();
    int rr = threadIdx.x / M, c = threadIdx.x - rr * M;
    int row = r0 + rr;
    if (row >= NN) return;
    float acc = 0.f;
#pragma unroll
    for (int k = 0; k < K; ++k) acc += a[rr][k] * W[k * M + c];
    if (BIAS) acc += bias[c];
    if (RELU) acc = fmaxf(acc, 0.f);
    C[(size_t)row * M + c] = acc;
}

// ---------------- aggregation: one wave per dst node, single pass ----------------
// softmax is shift-invariant; |e| is small here, exp is fp32-safe without max pass.

__global__ __launch_bounds__(256) void aggregate_kernel(
    const int* __restrict__ row_ptr, const int* __restrict__ ssrc,
    const float* __restrict__ feat, const float* __restrict__ el,
    const float* __restrict__ er, const float* __restrict__ bias,
    float* __restrict__ out) {
    int w = blockIdx.x * 4 + (threadIdx.x >> 6);
    if (w >= NN) return;
    int lane = threadIdx.x & 63;
    int beg = row_ptr[w], end = row_ptr[w + 1];
    float er0 = er[w * 3 + 0], er1 = er[w * 3 + 1], er2 = er[w * 3 + 2];

    float s0 = 0.f, s1 = 0.f, s2 = 0.f;
    float acc0 = 0.f, acc1 = 0.f, acc2 = 0.f;
    for (int e = beg; e < end; ++e) {
        int s = ssrc[e];
        float a0 = el[s * 3 + 0] + er0; a0 = a0 > 0.f ? a0 : NEG * a0;
        float a1 = el[s * 3 + 1] + er1; a1 = a1 > 0.f ? a1 : NEG * a1;
        float a2 = el[s * 3 + 2] + er2; a2 = a2 > 0.f ? a2 : NEG * a2;
        float w0 = __expf(a0), w1 = __expf(a1), w2 = __expf(a2);
        s0 += w0; s1 += w1; s2 += w2;
        const float* fr = feat + (size_t)s * FEAT;
        acc0 += w0 * fr[lane];
        acc1 += w1 * fr[64 + lane];
        acc2 += w2 * fr[128 + lane];
    }

    float r0, r1, r2;
    if (end > beg) { r0 = acc0 / s0; r1 = acc1 / s1; r2 = acc2 / s2; }
    else           { r0 = r1 = r2 = 0.f; }
    r0 += bias[lane]; r1 += bias[64 + lane]; r2 += bias[128 + lane];
    out[(size_t)w * FEAT + lane]       = fmaxf(r0, 0.f);
    out[(size_t)w * FEAT + 64 + lane]  = fmaxf(r1, 0.f);
    out[(size_t)w * FEAT + 128 + lane] = fmaxf(r2, 0.f);
}

// ---------------- launch ----------------

extern "C" void kernel_launch(void* const* d_in, const int* in_sizes, int n_in,
                              void* d_out, int out_size, void* d_ws, size_t ws_size,
                              hipStream_t stream) {
    const float* features = (const float*)d_in[0];
    const int*   src      = (const int*)d_in[1];
    const int*   dst      = (const int*)d_in[2];
    const float* W1  = (const float*)d_in[3];
    const float* al1 = (const float*)d_in[4];
    const float* ar1 = (const float*)d_in[5];
    const float* b1  = (const float*)d_in[6];
    const float* W2  = (const float*)d_in[7];
    const float* al2 = (const float*)d_in[8];
    const float* ar2 = (const float*)d_in[9];
    const float* b2  = (const float*)d_in[10];
    const float* w3  = (const float*)d_in[11];
    const float* b3  = (const float*)d_in[12];
    const float* w4  = (const float*)d_in[13];
    const float* b4  = (const float*)d_in[14];
    float* out = (float*)d_out;

    char* p = (char*)d_ws;
    float* feat = (float*)p; p += (size_t)NN * FEAT * 4;
    float* x    = (float*)p; p += (size_t)NN * FEAT * 4;
    float* el   = (float*)p; p += (size_t)NN * NH * 4;
    float* er   = (float*)p; p += (size_t)NN * NH * 4;
    int* counts  = (int*)p;  p += (size_t)NN * 4;
    int* row_ptr = (int*)p;  p += (size_t)(NN + 4) * 4;   // padded: keep cursor 16B-aligned
    int* cursor  = (int*)p;  p += (size_t)NN * 4;
    int* ssrc    = (int*)p;  p += (size_t)EE * 4;
    int* bsum    = (int*)p;  p += 128 * 4;

    const int GM = (NN + 63) / 64;   // 1563

    // CSR by dst (same for both layers)
    hipMemsetAsync(counts, 0, (size_t)NN * 4, stream);
    hist_kernel<<<(EE + 255) / 256, 256, 0, stream>>>(dst, counts);
    blocksum_kernel<<<NB, 256, 0, stream>>>(counts, bsum);
    scanb_kernel<<<1, 128, 0, stream>>>(bsum);
    scanfinal_kernel<<<NB, 256, 0, stream>>>(counts, bsum, row_ptr, cursor);
    scatter_kernel<<<(EE + 255) / 256, 256, 0, stream>>>(src, dst, cursor, ssrc);

    // ---- layer 1 ----
    gemm64_kernel<INF_, FEAT, false, false, true><<<dim3(GM, FEAT / 64), 256, 0, stream>>>(
        features, W1, nullptr, feat, al1, ar1, el, er);
    aggregate_kernel<<<(NN + 3) / 4, 256, 0, stream>>>(row_ptr, ssrc, feat, el, er, b1, x);

    // ---- layer 2 ----
    gemm64_kernel<FEAT, FEAT, false, false, true><<<dim3(GM, FEAT / 64), 256, 0, stream>>>(
        x, W2, nullptr, feat, al2, ar2, el, er);
    aggregate_kernel<<<(NN + 3) / 4, 256, 0, stream>>>(row_ptr, ssrc, feat, el, er, b2, x);

    // ---- MLP head ---- (reuse feat as hidden buffer)
    gemm64_kernel<FEAT, HIDF, true, true, false><<<dim3(GM, 1), 256, 0, stream>>>(
        x, w3, b3, feat, nullptr, nullptr, nullptr, nullptr);
    rowgemm_kernel<HIDF, OUTF, 16, true, false><<<NN / 16, 256, 0, stream>>>(feat, w4, b4, out);
}

// Round 8
// 907.876 us; speedup vs baseline: 2.3646x; 1.0405x over previous
//
#include <hip/hip_runtime.h>
#include <cstdint>
#include <cstddef>

#define NN   100000
#define EE   1600000
#define INF_ 128
#define HIDF 64
#define NH   3
#define FEAT 192   // NH*HIDF
#define OUTF 16
#define NEG  0.2f

#define NI4  25000   // NN/4
#define NB   98      // ceil(NN/1024)

typedef unsigned short ushort_t;
typedef unsigned int   uint_t;

__device__ __forceinline__ float bf2f(ushort_t u) {
    return __uint_as_float(((uint_t)u) << 16);
}
__device__ __forceinline__ ushort_t f2bf(float f) {   // round-to-nearest-even
    uint_t b = __float_as_uint(f);
    return (ushort_t)((b + 0x7FFFu + ((b >> 16) & 1u)) >> 16);
}

// ---------------- CSR build ----------------

__global__ void hist_kernel(const int* __restrict__ dst, int* __restrict__ counts) {
    int e = blockIdx.x * 256 + threadIdx.x;
    if (e < EE) atomicAdd(&counts[dst[e]], 1);
}

__global__ __launch_bounds__(256) void blocksum_kernel(const int* __restrict__ counts,
                                                       int* __restrict__ bsum) {
    int t = threadIdx.x;
    int idx4 = blockIdx.x * 256 + t;
    int s = 0;
    if (idx4 < NI4) {
        int4 v = ((const int4*)counts)[idx4];
        s = v.x + v.y + v.z + v.w;
    }
    __shared__ int sd[4];
    for (int o = 32; o; o >>= 1) s += __shfl_down(s, o, 64);
    if ((t & 63) == 0) sd[t >> 6] = s;
    __syncthreads();
    if (t == 0) bsum[blockIdx.x] = sd[0] + sd[1] + sd[2] + sd[3];
}

__global__ __launch_bounds__(128) void scanb_kernel(int* __restrict__ bsum) {
    __shared__ int sd[128];
    int t = threadIdx.x;
    int v = (t < NB) ? bsum[t] : 0;
    sd[t] = v;
    __syncthreads();
    for (int o = 1; o < 128; o <<= 1) {
        int u = (t >= o) ? sd[t - o] : 0;
        __syncthreads();
        sd[t] += u;
        __syncthreads();
    }
    if (t < NB) bsum[t] = sd[t] - v;   // exclusive
}

__global__ __launch_bounds__(256) void scanfinal_kernel(const int* __restrict__ counts,
                                                        const int* __restrict__ bsum,
                                                        int* __restrict__ row_ptr,
                                                        int* __restrict__ cursor) {
    __shared__ int sd[256];
    int t = threadIdx.x;
    int idx4 = blockIdx.x * 256 + t;
    int4 v = make_int4(0, 0, 0, 0);
    if (idx4 < NI4) v = ((const int4*)counts)[idx4];
    int s = v.x + v.y + v.z + v.w;
    sd[t] = s;
    __syncthreads();
    for (int o = 1; o < 256; o <<= 1) {
        int u = (t >= o) ? sd[t - o] : 0;
        __syncthreads();
        sd[t] += u;
        __syncthreads();
    }
    int base = bsum[blockIdx.x] + sd[t] - s;
    if (idx4 < NI4) {
        int4 r;
        r.x = base;
        r.y = base + v.x;
        r.z = base + v.x + v.y;
        r.w = base + v.x + v.y + v.z;
        ((int4*)row_ptr)[idx4] = r;
        ((int4*)cursor)[idx4]  = r;
    }
    if (blockIdx.x == 0 && t == 0) row_ptr[NN] = EE;
}

__global__ void scatter_kernel(const int* __restrict__ src, const int* __restrict__ dst,
                               int* __restrict__ cursor, int* __restrict__ ssrc) {
    int e = blockIdx.x * 256 + threadIdx.x;
    if (e < EE) {
        int p = atomicAdd(&cursor[dst[e]], 1);
        ssrc[p] = src[e];
    }
}

// ---------------- tiled fp32 GEMM: 64x64 tile, BK=32, 4x4/thread ----------------
// A_BF16: A operand is bf16 (converted to fp32 in LDS staging).
// C_BF16: C written as bf16.  ELER: fused el/er head dot products (blockIdx.y = head).

template <int K, int N, bool BIAS, bool RELU, bool ELER, bool A_BF16, bool C_BF16>
__global__ __launch_bounds__(256) void gemm64_kernel(const void* __restrict__ Av,
                                                     const float* __restrict__ B,
                                                     const float* __restrict__ bias,
                                                     void* __restrict__ Cv,
                                                     const float* __restrict__ al,
                                                     const float* __restrict__ ar,
                                                     float* __restrict__ el,
                                                     float* __restrict__ er) {
    __shared__ float As[32][64];   // [k][m] (transposed)
    __shared__ float Bs[32][64];   // [k][n]
    const int m0 = blockIdx.x * 64;
    const int n0 = blockIdx.y * 64;
    const int t  = threadIdx.x;
    const int tr = t >> 4;
    const int tc = t & 15;

    float acc[4][4] = {};

    for (int kt = 0; kt < K; kt += 32) {
        if (A_BF16) {
            const ushort_t* A = (const ushort_t*)Av;
            // 64 rows x 32 cols = 2048 bf16; 8 per thread (one 16B load)
            int row = t >> 2, c8 = (t & 3) * 8;
            int gr = m0 + row;
            if (gr < NN) {
                uint4 v = *(const uint4*)(A + (size_t)gr * K + kt + c8);
                As[c8 + 0][row] = bf2f((ushort_t)(v.x & 0xffff));
                As[c8 + 1][row] = bf2f((ushort_t)(v.x >> 16));
                As[c8 + 2][row] = bf2f((ushort_t)(v.y & 0xffff));
                As[c8 + 3][row] = bf2f((ushort_t)(v.y >> 16));
                As[c8 + 4][row] = bf2f((ushort_t)(v.z & 0xffff));
                As[c8 + 5][row] = bf2f((ushort_t)(v.z >> 16));
                As[c8 + 6][row] = bf2f((ushort_t)(v.w & 0xffff));
                As[c8 + 7][row] = bf2f((ushort_t)(v.w >> 16));
            } else {
#pragma unroll
                for (int j = 0; j < 8; ++j) As[c8 + j][row] = 0.f;
            }
        } else {
            const float* A = (const float*)Av;
            int f = t;
#pragma unroll
            for (int it = 0; it < 2; ++it, f += 256) {
                int row = f >> 3, c4 = (f & 7) * 4;
                float4 v = make_float4(0.f, 0.f, 0.f, 0.f);
                int gr = m0 + row;
                if (gr < NN) v = *(const float4*)(A + (size_t)gr * K + kt + c4);
                As[c4 + 0][row] = v.x;
                As[c4 + 1][row] = v.y;
                As[c4 + 2][row] = v.z;
                As[c4 + 3][row] = v.w;
            }
        }
        {
            int f = t;
#pragma unroll
            for (int it = 0; it < 2; ++it, f += 256) {
                int row = f >> 4, c4 = (f & 15) * 4;
                *(float4*)&Bs[row][c4] = *(const float4*)(B + (size_t)(kt + row) * N + n0 + c4);
            }
        }
        __syncthreads();
#pragma unroll
        for (int k = 0; k < 32; ++k) {
            float4 a = *(const float4*)&As[k][tr * 4];
            float4 b = *(const float4*)&Bs[k][tc * 4];
            acc[0][0] += a.x * b.x; acc[0][1] += a.x * b.y; acc[0][2] += a.x * b.z; acc[0][3] += a.x * b.w;
            acc[1][0] += a.y * b.x; acc[1][1] += a.y * b.y; acc[1][2] += a.y * b.z; acc[1][3] += a.y * b.w;
            acc[2][0] += a.z * b.x; acc[2][1] += a.z * b.y; acc[2][2] += a.z * b.z; acc[2][3] += a.z * b.w;
            acc[3][0] += a.w * b.x; acc[3][1] += a.w * b.y; acc[3][2] += a.w * b.z; acc[3][3] += a.w * b.w;
        }
        __syncthreads();
    }

    float4 bv = make_float4(0.f, 0.f, 0.f, 0.f);
    if (BIAS) bv = *(const float4*)(bias + n0 + tc * 4);
#pragma unroll
    for (int i = 0; i < 4; ++i) {
        int row = m0 + tr * 4 + i;
        if (row >= NN) continue;
        float4 r;
        r.x = acc[i][0]; r.y = acc[i][1]; r.z = acc[i][2]; r.w = acc[i][3];
        if (BIAS) { r.x += bv.x; r.y += bv.y; r.z += bv.z; r.w += bv.w; }
        if (RELU) {
            r.x = fmaxf(r.x, 0.f); r.y = fmaxf(r.y, 0.f);
            r.z = fmaxf(r.z, 0.f); r.w = fmaxf(r.w, 0.f);
        }
        if (C_BF16) {
            ushort4 u;
            u.x = f2bf(r.x); u.y = f2bf(r.y); u.z = f2bf(r.z); u.w = f2bf(r.w);
            *(ushort4*)((ushort_t*)Cv + (size_t)row * N + n0 + tc * 4) = u;
        } else {
            *(float4*)((float*)Cv + (size_t)row * N + n0 + tc * 4) = r;
        }
    }

    if (ELER) {
        const int h = blockIdx.y;
        float4 va = *(const float4*)(al + h * HIDF + tc * 4);
        float4 vb = *(const float4*)(ar + h * HIDF + tc * 4);
#pragma unroll
        for (int i = 0; i < 4; ++i) {
            float pl = acc[i][0] * va.x + acc[i][1] * va.y + acc[i][2] * va.z + acc[i][3] * va.w;
            float pr = acc[i][0] * vb.x + acc[i][1] * vb.y + acc[i][2] * vb.z + acc[i][3] * vb.w;
#pragma unroll
            for (int o = 1; o < 16; o <<= 1) {
                pl += __shfl_xor(pl, o, 16);
                pr += __shfl_xor(pr, o, 16);
            }
            int row = m0 + tr * 4 + i;
            if (tc == 0 && row < NN) {
                el[row * NH + h] = pl;
                er[row * NH + h] = pr;
            }
        }
    }
}

// ---------------- small GEMM for the 64->16 head (fp32) ----------------

template <int K, int M, int ROWS, bool BIAS, bool RELU>
__global__ void rowgemm_kernel(const float* __restrict__ A, const float* __restrict__ W,
                               const float* __restrict__ bias, float* __restrict__ C) {
    __shared__ float a[ROWS][K];
    const int BT = M * ROWS;
    int r0 = blockIdx.x * ROWS;
    for (int i = threadIdx.x; i < ROWS * K; i += BT) {
        int rr = i / K, kk = i - rr * K;
        int row = r0 + rr;
        a[rr][kk] = (row < NN) ? A[(size_t)row * K + kk] : 0.f;
    }
    __syncthreads();
    int rr = threadIdx.x / M, c = threadIdx.x - rr * M;
    int row = r0 + rr;
    if (row >= NN) return;
    float acc = 0.f;
#pragma unroll
    for (int k = 0; k < K; ++k) acc += a[rr][k] * W[k * M + c];
    if (BIAS) acc += bias[c];
    if (RELU) acc = fmaxf(acc, 0.f);
    C[(size_t)row * M + c] = acc;
}

// ---------------- aggregation: one wave per dst node, bf16 gather ----------------

__global__ __launch_bounds__(256) void aggregate_kernel(
    const int* __restrict__ row_ptr, const int* __restrict__ ssrc,
    const ushort_t* __restrict__ featb, const float* __restrict__ el,
    const float* __restrict__ er, const float* __restrict__ bias,
    ushort_t* __restrict__ outb) {
    int w = blockIdx.x * 4 + (threadIdx.x >> 6);
    if (w >= NN) return;
    int lane = threadIdx.x & 63;
    int beg = row_ptr[w], end = row_ptr[w + 1];
    float er0 = er[w * 3 + 0], er1 = er[w * 3 + 1], er2 = er[w * 3 + 2];

    float s0 = 0.f, s1 = 0.f, s2 = 0.f;
    float acc0 = 0.f, acc1 = 0.f, acc2 = 0.f;
    for (int e = beg; e < end; ++e) {
        int s = ssrc[e];
        float a0 = el[s * 3 + 0] + er0; a0 = a0 > 0.f ? a0 : NEG * a0;
        float a1 = el[s * 3 + 1] + er1; a1 = a1 > 0.f ? a1 : NEG * a1;
        float a2 = el[s * 3 + 2] + er2; a2 = a2 > 0.f ? a2 : NEG * a2;
        float w0 = __expf(a0), w1 = __expf(a1), w2 = __expf(a2);
        s0 += w0; s1 += w1; s2 += w2;
        const ushort_t* fr = featb + (size_t)s * FEAT;
        acc0 += w0 * bf2f(fr[lane]);
        acc1 += w1 * bf2f(fr[64 + lane]);
        acc2 += w2 * bf2f(fr[128 + lane]);
    }

    float r0, r1, r2;
    if (end > beg) { r0 = acc0 / s0; r1 = acc1 / s1; r2 = acc2 / s2; }
    else           { r0 = r1 = r2 = 0.f; }
    r0 += bias[lane]; r1 += bias[64 + lane]; r2 += bias[128 + lane];
    outb[(size_t)w * FEAT + lane]       = f2bf(fmaxf(r0, 0.f));
    outb[(size_t)w * FEAT + 64 + lane]  = f2bf(fmaxf(r1, 0.f));
    outb[(size_t)w * FEAT + 128 + lane] = f2bf(fmaxf(r2, 0.f));
}

// ---------------- launch ----------------

extern "C" void kernel_launch(void* const* d_in, const int* in_sizes, int n_in,
                              void* d_out, int out_size, void* d_ws, size_t ws_size,
                              hipStream_t stream) {
    const float* features = (const float*)d_in[0];
    const int*   src      = (const int*)d_in[1];
    const int*   dst      = (const int*)d_in[2];
    const float* W1  = (const float*)d_in[3];
    const float* al1 = (const float*)d_in[4];
    const float* ar1 = (const float*)d_in[5];
    const float* b1  = (const float*)d_in[6];
    const float* W2  = (const float*)d_in[7];
    const float* al2 = (const float*)d_in[8];
    const float* ar2 = (const float*)d_in[9];
    const float* b2  = (const float*)d_in[10];
    const float* w3  = (const float*)d_in[11];
    const float* b3  = (const float*)d_in[12];
    const float* w4  = (const float*)d_in[13];
    const float* b4  = (const float*)d_in[14];
    float* out = (float*)d_out;

    char* p = (char*)d_ws;
    ushort_t* featb = (ushort_t*)p; p += (size_t)NN * FEAT * 2;   // bf16 projected feats
    ushort_t* xb    = (ushort_t*)p; p += (size_t)NN * FEAT * 2;   // bf16 layer outputs
    float* hid = (float*)p; p += (size_t)NN * HIDF * 4;           // fp32 MLP hidden
    float* el  = (float*)p; p += (size_t)NN * NH * 4;
    float* er  = (float*)p; p += (size_t)NN * NH * 4;
    int* counts  = (int*)p;  p += (size_t)NN * 4;
    int* row_ptr = (int*)p;  p += (size_t)(NN + 4) * 4;
    int* cursor  = (int*)p;  p += (size_t)NN * 4;
    int* ssrc    = (int*)p;  p += (size_t)EE * 4;
    int* bsum    = (int*)p;  p += 128 * 4;

    const int GM = (NN + 63) / 64;   // 1563

    // CSR by dst
    hipMemsetAsync(counts, 0, (size_t)NN * 4, stream);
    hist_kernel<<<(EE + 255) / 256, 256, 0, stream>>>(dst, counts);
    blocksum_kernel<<<NB, 256, 0, stream>>>(counts, bsum);
    scanb_kernel<<<1, 128, 0, stream>>>(bsum);
    scanfinal_kernel<<<NB, 256, 0, stream>>>(counts, bsum, row_ptr, cursor);
    scatter_kernel<<<(EE + 255) / 256, 256, 0, stream>>>(src, dst, cursor, ssrc);

    // ---- layer 1 ----  A=fp32 features, C=bf16 featb, fused el/er
    gemm64_kernel<INF_, FEAT, false, false, true, false, true>
        <<<dim3(GM, FEAT / 64), 256, 0, stream>>>(features, W1, nullptr, featb, al1, ar1, el, er);
    aggregate_kernel<<<(NN + 3) / 4, 256, 0, stream>>>(row_ptr, ssrc, featb, el, er, b1, xb);

    // ---- layer 2 ----  A=bf16 xb, C=bf16 featb, fused el/er
    gemm64_kernel<FEAT, FEAT, false, false, true, true, true>
        <<<dim3(GM, FEAT / 64), 256, 0, stream>>>(xb, W2, nullptr, featb, al2, ar2, el, er);
    aggregate_kernel<<<(NN + 3) / 4, 256, 0, stream>>>(row_ptr, ssrc, featb, el, er, b2, xb);

    // ---- MLP head ----  A=bf16 xb, C=fp32 hid
    gemm64_kernel<FEAT, HIDF, true, true, false, true, false>
        <<<dim3(GM, 1), 256, 0, stream>>>(xb, w3, b3, hid, nullptr, nullptr, nullptr, nullptr);
    rowgemm_kernel<HIDF, OUTF, 16, true, false><<<NN / 16, 256, 0, stream>>>(hid, w4, b4, out);
}

// Round 12
// 889.488 us; speedup vs baseline: 2.4135x; 1.0207x over previous
//
#include <hip/hip_runtime.h>
#include <cstdint>
#include <cstddef>

#define NN   100000
#define EE   1600000
#define INF_ 128
#define HIDF 64
#define NH   3
#define FEAT 192   // NH*HIDF
#define OUTF 16
#define NEG  0.2f

#define NI4  25000   // NN/4
#define NB   98      // ceil(NN/1024)

typedef unsigned short ushort_t;
typedef unsigned int   uint_t;

__device__ __forceinline__ float bf2f(ushort_t u) {
    return __uint_as_float(((uint_t)u) << 16);
}
__device__ __forceinline__ ushort_t f2bf(float f) {   // round-to-nearest-even
    uint_t b = __float_as_uint(f);
    return (ushort_t)((b + 0x7FFFu + ((b >> 16) & 1u)) >> 16);
}

// ---------------- CSR build ----------------

__global__ void hist_kernel(const int* __restrict__ dst, int* __restrict__ counts) {
    int e = blockIdx.x * 256 + threadIdx.x;
    if (e < EE) atomicAdd(&counts[dst[e]], 1);
}

__global__ __launch_bounds__(256) void blocksum_kernel(const int* __restrict__ counts,
                                                       int* __restrict__ bsum) {
    int t = threadIdx.x;
    int idx4 = blockIdx.x * 256 + t;
    int s = 0;
    if (idx4 < NI4) {
        int4 v = ((const int4*)counts)[idx4];
        s = v.x + v.y + v.z + v.w;
    }
    __shared__ int sd[4];
    for (int o = 32; o; o >>= 1) s += __shfl_down(s, o, 64);
    if ((t & 63) == 0) sd[t >> 6] = s;
    __syncthreads();
    if (t == 0) bsum[blockIdx.x] = sd[0] + sd[1] + sd[2] + sd[3];
}

__global__ __launch_bounds__(128) void scanb_kernel(int* __restrict__ bsum) {
    __shared__ int sd[128];
    int t = threadIdx.x;
    int v = (t < NB) ? bsum[t] : 0;
    sd[t] = v;
    __syncthreads();
    for (int o = 1; o < 128; o <<= 1) {
        int u = (t >= o) ? sd[t - o] : 0;
        __syncthreads();
        sd[t] += u;
        __syncthreads();
    }
    if (t < NB) bsum[t] = sd[t] - v;   // exclusive
}

__global__ __launch_bounds__(256) void scanfinal_kernel(const int* __restrict__ counts,
                                                        const int* __restrict__ bsum,
                                                        int* __restrict__ row_ptr,
                                                        int* __restrict__ cursor) {
    __shared__ int sd[256];
    int t = threadIdx.x;
    int idx4 = blockIdx.x * 256 + t;
    int4 v = make_int4(0, 0, 0, 0);
    if (idx4 < NI4) v = ((const int4*)counts)[idx4];
    int s = v.x + v.y + v.z + v.w;
    sd[t] = s;
    __syncthreads();
    for (int o = 1; o < 256; o <<= 1) {
        int u = (t >= o) ? sd[t - o] : 0;
        __syncthreads();
        sd[t] += u;
        __syncthreads();
    }
    int base = bsum[blockIdx.x] + sd[t] - s;
    if (idx4 < NI4) {
        int4 r;
        r.x = base;
        r.y = base + v.x;
        r.z = base + v.x + v.y;
        r.w = base + v.x + v.y + v.z;
        ((int4*)row_ptr)[idx4] = r;
        ((int4*)cursor)[idx4]  = r;
    }
    if (blockIdx.x == 0 && t == 0) row_ptr[NN] = EE;
}

__global__ void scatter_kernel(const int* __restrict__ src, const int* __restrict__ dst,
                               int* __restrict__ cursor, int* __restrict__ ssrc,
                               int* __restrict__ sdst) {
    int e = blockIdx.x * 256 + threadIdx.x;
    if (e < EE) {
        int d = dst[e];
        int p = atomicAdd(&cursor[d], 1);
        ssrc[p] = src[e];
        sdst[p] = d;
    }
}

// ---------------- edge weights: one thread per CSR slot ----------------
// wgt[p*3+h] = exp(leakyrelu(el[src,h] + er[dst,h])); el/er are 1.2MB (L2-hot).

__global__ __launch_bounds__(256) void edgew_kernel(const int* __restrict__ ssrc,
                                                    const int* __restrict__ sdst,
                                                    const float* __restrict__ el,
                                                    const float* __restrict__ er,
                                                    float* __restrict__ wgt) {
    int p = blockIdx.x * 256 + threadIdx.x;
    if (p >= EE) return;
    int s = ssrc[p], d = sdst[p];
    float a0 = el[s * 3 + 0] + er[d * 3 + 0]; a0 = a0 > 0.f ? a0 : NEG * a0;
    float a1 = el[s * 3 + 1] + er[d * 3 + 1]; a1 = a1 > 0.f ? a1 : NEG * a1;
    float a2 = el[s * 3 + 2] + er[d * 3 + 2]; a2 = a2 > 0.f ? a2 : NEG * a2;
    wgt[p * 3 + 0] = __expf(a0);
    wgt[p * 3 + 1] = __expf(a1);
    wgt[p * 3 + 2] = __expf(a2);
}

// ---------------- tiled fp32 GEMM: 64x64 tile, BK=32, 4x4/thread ----------------
// A_BF16: A operand is bf16 (converted to fp32 in LDS staging).
// C_BF16: C written as bf16.  ELER: fused el/er head dot products (blockIdx.y = head).

template <int K, int N, bool BIAS, bool RELU, bool ELER, bool A_BF16, bool C_BF16>
__global__ __launch_bounds__(256) void gemm64_kernel(const void* __restrict__ Av,
                                                     const float* __restrict__ B,
                                                     const float* __restrict__ bias,
                                                     void* __restrict__ Cv,
                                                     const float* __restrict__ al,
                                                     const float* __restrict__ ar,
                                                     float* __restrict__ el,
                                                     float* __restrict__ er) {
    __shared__ float As[32][64];   // [k][m] (transposed)
    __shared__ float Bs[32][64];   // [k][n]
    const int m0 = blockIdx.x * 64;
    const int n0 = blockIdx.y * 64;
    const int t  = threadIdx.x;
    const int tr = t >> 4;
    const int tc = t & 15;

    float acc[4][4] = {};

    for (int kt = 0; kt < K; kt += 32) {
        if (A_BF16) {
            const ushort_t* A = (const ushort_t*)Av;
            int row = t >> 2, c8 = (t & 3) * 8;
            int gr = m0 + row;
            if (gr < NN) {
                uint4 v = *(const uint4*)(A + (size_t)gr * K + kt + c8);
                As[c8 + 0][row] = bf2f((ushort_t)(v.x & 0xffff));
                As[c8 + 1][row] = bf2f((ushort_t)(v.x >> 16));
                As[c8 + 2][row] = bf2f((ushort_t)(v.y & 0xffff));
                As[c8 + 3][row] = bf2f((ushort_t)(v.y >> 16));
                As[c8 + 4][row] = bf2f((ushort_t)(v.z & 0xffff));
                As[c8 + 5][row] = bf2f((ushort_t)(v.z >> 16));
                As[c8 + 6][row] = bf2f((ushort_t)(v.w & 0xffff));
                As[c8 + 7][row] = bf2f((ushort_t)(v.w >> 16));
            } else {
#pragma unroll
                for (int j = 0; j < 8; ++j) As[c8 + j][row] = 0.f;
            }
        } else {
            const float* A = (const float*)Av;
            int f = t;
#pragma unroll
            for (int it = 0; it < 2; ++it, f += 256) {
                int row = f >> 3, c4 = (f & 7) * 4;
                float4 v = make_float4(0.f, 0.f, 0.f, 0.f);
                int gr = m0 + row;
                if (gr < NN) v = *(const float4*)(A + (size_t)gr * K + kt + c4);
                As[c4 + 0][row] = v.x;
                As[c4 + 1][row] = v.y;
                As[c4 + 2][row] = v.z;
                As[c4 + 3][row] = v.w;
            }
        }
        {
            int f = t;
#pragma unroll
            for (int it = 0; it < 2; ++it, f += 256) {
                int row = f >> 4, c4 = (f & 15) * 4;
                *(float4*)&Bs[row][c4] = *(const float4*)(B + (size_t)(kt + row) * N + n0 + c4);
            }
        }
        __syncthreads();
#pragma unroll
        for (int k = 0; k < 32; ++k) {
            float4 a = *(const float4*)&As[k][tr * 4];
            float4 b = *(const float4*)&Bs[k][tc * 4];
            acc[0][0] += a.x * b.x; acc[0][1] += a.x * b.y; acc[0][2] += a.x * b.z; acc[0][3] += a.x * b.w;
            acc[1][0] += a.y * b.x; acc[1][1] += a.y * b.y; acc[1][2] += a.y * b.z; acc[1][3] += a.y * b.w;
            acc[2][0] += a.z * b.x; acc[2][1] += a.z * b.y; acc[2][2] += a.z * b.z; acc[2][3] += a.z * b.w;
            acc[3][0] += a.w * b.x; acc[3][1] += a.w * b.y; acc[3][2] += a.w * b.z; acc[3][3] += a.w * b.w;
        }
        __syncthreads();
    }

    float4 bv = make_float4(0.f, 0.f, 0.f, 0.f);
    if (BIAS) bv = *(const float4*)(bias + n0 + tc * 4);
#pragma unroll
    for (int i = 0; i < 4; ++i) {
        int row = m0 + tr * 4 + i;
        if (row >= NN) continue;
        float4 r;
        r.x = acc[i][0]; r.y = acc[i][1]; r.z = acc[i][2]; r.w = acc[i][3];
        if (BIAS) { r.x += bv.x; r.y += bv.y; r.z += bv.z; r.w += bv.w; }
        if (RELU) {
            r.x = fmaxf(r.x, 0.f); r.y = fmaxf(r.y, 0.f);
            r.z = fmaxf(r.z, 0.f); r.w = fmaxf(r.w, 0.f);
        }
        if (C_BF16) {
            ushort4 u;
            u.x = f2bf(r.x); u.y = f2bf(r.y); u.z = f2bf(r.z); u.w = f2bf(r.w);
            *(ushort4*)((ushort_t*)Cv + (size_t)row * N + n0 + tc * 4) = u;
        } else {
            *(float4*)((float*)Cv + (size_t)row * N + n0 + tc * 4) = r;
        }
    }

    if (ELER) {
        const int h = blockIdx.y;
        float4 va = *(const float4*)(al + h * HIDF + tc * 4);
        float4 vb = *(const float4*)(ar + h * HIDF + tc * 4);
#pragma unroll
        for (int i = 0; i < 4; ++i) {
            float pl = acc[i][0] * va.x + acc[i][1] * va.y + acc[i][2] * va.z + acc[i][3] * va.w;
            float pr = acc[i][0] * vb.x + acc[i][1] * vb.y + acc[i][2] * vb.z + acc[i][3] * vb.w;
#pragma unroll
            for (int o = 1; o < 16; o <<= 1) {
                pl += __shfl_xor(pl, o, 16);
                pr += __shfl_xor(pr, o, 16);
            }
            int row = m0 + tr * 4 + i;
            if (tc == 0 && row < NN) {
                el[row * NH + h] = pl;
                er[row * NH + h] = pr;
            }
        }
    }
}

// ---------------- small GEMM for the 64->16 head (fp32) ----------------

template <int K, int M, int ROWS, bool BIAS, bool RELU>
__global__ void rowgemm_kernel(const float* __restrict__ A, const float* __restrict__ W,
                               const float* __restrict__ bias, float* __restrict__ C) {
    __shared__ float a[ROWS][K];
    const int BT = M * ROWS;
    int r0 = blockIdx.x * ROWS;
    for (int i = threadIdx.x; i < ROWS * K; i += BT) {
        int rr = i / K, kk = i - rr * K;
        int row = r0 + rr;
        a[rr][kk] = (row < NN) ? A[(size_t)row * K + kk] : 0.f;
    }
    __syncthreads();
    int rr = threadIdx.x / M, c = threadIdx.x - rr * M;
    int row = r0 + rr;
    if (row >= NN) return;
    float acc = 0.f;
#pragma unroll
    for (int k = 0; k < K; ++k) acc += a[rr][k] * W[k * M + c];
    if (BIAS) acc += bias[c];
    if (RELU) acc = fmaxf(acc, 0.f);
    C[(size_t)row * M + c] = acc;
}

// ---------------- aggregation: one wave per dst node, precomputed weights ----------------
// inner loop: broadcast ssrc/wgt (sequential, cache-hot) + 3 coalesced bf16 gathers + 6 FMA/add.

__global__ __launch_bounds__(256) void aggregate_kernel(
    const int* __restrict__ row_ptr, const int* __restrict__ ssrc,
    const float* __restrict__ wgt,
    const ushort_t* __restrict__ featb, const float* __restrict__ bias,
    ushort_t* __restrict__ outb) {
    int w = blockIdx.x * 4 + (threadIdx.x >> 6);
    if (w >= NN) return;
    int lane = threadIdx.x & 63;
    int beg = row_ptr[w], end = row_ptr[w + 1];

    float s0 = 0.f, s1 = 0.f, s2 = 0.f;
    float acc0 = 0.f, acc1 = 0.f, acc2 = 0.f;
    for (int p = beg; p < end; ++p) {
        int s = __builtin_amdgcn_readfirstlane(ssrc[p]);
        float w0 = wgt[p * 3 + 0];
        float w1 = wgt[p * 3 + 1];
        float w2 = wgt[p * 3 + 2];
        s0 += w0; s1 += w1; s2 += w2;
        const ushort_t* fr = featb + (size_t)s * FEAT;
        acc0 += w0 * bf2f(fr[lane]);
        acc1 += w1 * bf2f(fr[64 + lane]);
        acc2 += w2 * bf2f(fr[128 + lane]);
    }

    float r0, r1, r2;
    if (end > beg) { r0 = acc0 / s0; r1 = acc1 / s1; r2 = acc2 / s2; }
    else           { r0 = r1 = r2 = 0.f; }
    r0 += bias[lane]; r1 += bias[64 + lane]; r2 += bias[128 + lane];
    outb[(size_t)w * FEAT + lane]       = f2bf(fmaxf(r0, 0.f));
    outb[(size_t)w * FEAT + 64 + lane]  = f2bf(fmaxf(r1, 0.f));
    outb[(size_t)w * FEAT + 128 + lane] = f2bf(fmaxf(r2, 0.f));
}

// ---------------- launch ----------------

extern "C" void kernel_launch(void* const* d_in, const int* in_sizes, int n_in,
                              void* d_out, int out_size, void* d_ws, size_t ws_size,
                              hipStream_t stream) {
    const float* features = (const float*)d_in[0];
    const int*   src      = (const int*)d_in[1];
    const int*   dst      = (const int*)d_in[2];
    const float* W1  = (const float*)d_in[3];
    const float* al1 = (const float*)d_in[4];
    const float* ar1 = (const float*)d_in[5];
    const float* b1  = (const float*)d_in[6];
    const float* W2  = (const float*)d_in[7];
    const float* al2 = (const float*)d_in[8];
    const float* ar2 = (const float*)d_in[9];
    const float* b2  = (const float*)d_in[10];
    const float* w3  = (const float*)d_in[11];
    const float* b3  = (const float*)d_in[12];
    const float* w4  = (const float*)d_in[13];
    const float* b4  = (const float*)d_in[14];
    float* out = (float*)d_out;

    char* p = (char*)d_ws;
    ushort_t* featb = (ushort_t*)p; p += (size_t)NN * FEAT * 2;    // bf16 projected feats
    ushort_t* xb    = (ushort_t*)p; p += (size_t)NN * FEAT * 2;    // bf16 layer outputs
    float* scratch  = (float*)p;    p += (size_t)NN * HIDF * 4;    // wgt (layers) / hid (head) - disjoint use
    float* el  = (float*)p; p += (size_t)NN * NH * 4;
    float* er  = (float*)p; p += (size_t)NN * NH * 4;
    int* counts  = (int*)p;  p += (size_t)NN * 4;
    int* row_ptr = (int*)p;  p += (size_t)(NN + 4) * 4;
    int* cursor  = (int*)p;  p += (size_t)NN * 4;
    int* ssrc    = (int*)p;  p += (size_t)EE * 4;
    int* sdst    = (int*)p;  p += (size_t)EE * 4;
    int* bsum    = (int*)p;  p += 128 * 4;

    float* wgt = scratch;   // E*3*4 = 19.2MB <= 25.6MB
    float* hid = scratch;   // used only after last aggregate

    const int GM = (NN + 63) / 64;   // 1563
    const int GE = (EE + 255) / 256; // 6250

    // CSR by dst
    hipMemsetAsync(counts, 0, (size_t)NN * 4, stream);
    hist_kernel<<<GE, 256, 0, stream>>>(dst, counts);
    blocksum_kernel<<<NB, 256, 0, stream>>>(counts, bsum);
    scanb_kernel<<<1, 128, 0, stream>>>(bsum);
    scanfinal_kernel<<<NB, 256, 0, stream>>>(counts, bsum, row_ptr, cursor);
    scatter_kernel<<<GE, 256, 0, stream>>>(src, dst, cursor, ssrc, sdst);

    // ---- layer 1 ----
    gemm64_kernel<INF_, FEAT, false, false, true, false, true>
        <<<dim3(GM, FEAT / 64), 256, 0, stream>>>(features, W1, nullptr, featb, al1, ar1, el, er);
    edgew_kernel<<<GE, 256, 0, stream>>>(ssrc, sdst, el, er, wgt);
    aggregate_kernel<<<(NN + 3) / 4, 256, 0, stream>>>(row_ptr, ssrc, wgt, featb, b1, xb);

    // ---- layer 2 ----
    gemm64_kernel<FEAT, FEAT, false, false, true, true, true>
        <<<dim3(GM, FEAT / 64), 256, 0, stream>>>(xb, W2, nullptr, featb, al2, ar2, el, er);
    edgew_kernel<<<GE, 256, 0, stream>>>(ssrc, sdst, el, er, wgt);
    aggregate_kernel<<<(NN + 3) / 4, 256, 0, stream>>>(row_ptr, ssrc, wgt, featb, b2, xb);

    // ---- MLP head ----
    gemm64_kernel<FEAT, HIDF, true, true, false, true, false>
        <<<dim3(GM, 1), 256, 0, stream>>>(xb, w3, b3, hid, nullptr, nullptr, nullptr, nullptr);
    rowgemm_kernel<HIDF, OUTF, 16, true, false><<<NN / 16, 256, 0, stream>>>(hid, w4, b4, out);
}

// Round 13
// 779.038 us; speedup vs baseline: 2.7557x; 1.1418x over previous
//
#include <hip/hip_runtime.h>
#include <cstdint>
#include <cstddef>

#define NN   100000
#define EE   1600000
#define INF_ 128
#define HIDF 64
#define NH   3
#define FEAT 192   // NH*HIDF
#define OUTF 16
#define NEG  0.2f

#define NI4  25000   // NN/4
#define NB   98      // ceil(NN/1024)

typedef unsigned short ushort_t;
typedef unsigned int   uint_t;

__device__ __forceinline__ float bf2f(ushort_t u) {
    return __uint_as_float(((uint_t)u) << 16);
}
__device__ __forceinline__ ushort_t f2bf(float f) {   // round-to-nearest-even
    uint_t b = __float_as_uint(f);
    return (ushort_t)((b + 0x7FFFu + ((b >> 16) & 1u)) >> 16);
}

// ---------------- CSR build ----------------

__global__ void hist_kernel(const int* __restrict__ dst, int* __restrict__ counts) {
    int e = blockIdx.x * 256 + threadIdx.x;
    if (e < EE) atomicAdd(&counts[dst[e]], 1);
}

__global__ __launch_bounds__(256) void blocksum_kernel(const int* __restrict__ counts,
                                                       int* __restrict__ bsum) {
    int t = threadIdx.x;
    int idx4 = blockIdx.x * 256 + t;
    int s = 0;
    if (idx4 < NI4) {
        int4 v = ((const int4*)counts)[idx4];
        s = v.x + v.y + v.z + v.w;
    }
    __shared__ int sd[4];
    for (int o = 32; o; o >>= 1) s += __shfl_down(s, o, 64);
    if ((t & 63) == 0) sd[t >> 6] = s;
    __syncthreads();
    if (t == 0) bsum[blockIdx.x] = sd[0] + sd[1] + sd[2] + sd[3];
}

__global__ __launch_bounds__(128) void scanb_kernel(int* __restrict__ bsum) {
    __shared__ int sd[128];
    int t = threadIdx.x;
    int v = (t < NB) ? bsum[t] : 0;
    sd[t] = v;
    __syncthreads();
    for (int o = 1; o < 128; o <<= 1) {
        int u = (t >= o) ? sd[t - o] : 0;
        __syncthreads();
        sd[t] += u;
        __syncthreads();
    }
    if (t < NB) bsum[t] = sd[t] - v;   // exclusive
}

__global__ __launch_bounds__(256) void scanfinal_kernel(const int* __restrict__ counts,
                                                        const int* __restrict__ bsum,
                                                        int* __restrict__ row_ptr,
                                                        int* __restrict__ cursor) {
    __shared__ int sd[256];
    int t = threadIdx.x;
    int idx4 = blockIdx.x * 256 + t;
    int4 v = make_int4(0, 0, 0, 0);
    if (idx4 < NI4) v = ((const int4*)counts)[idx4];
    int s = v.x + v.y + v.z + v.w;
    sd[t] = s;
    __syncthreads();
    for (int o = 1; o < 256; o <<= 1) {
        int u = (t >= o) ? sd[t - o] : 0;
        __syncthreads();
        sd[t] += u;
        __syncthreads();
    }
    int base = bsum[blockIdx.x] + sd[t] - s;
    if (idx4 < NI4) {
        int4 r;
        r.x = base;
        r.y = base + v.x;
        r.z = base + v.x + v.y;
        r.w = base + v.x + v.y + v.z;
        ((int4*)row_ptr)[idx4] = r;
        ((int4*)cursor)[idx4]  = r;
    }
    if (blockIdx.x == 0 && t == 0) row_ptr[NN] = EE;
}

__global__ void scatter_kernel(const int* __restrict__ src, const int* __restrict__ dst,
                               int* __restrict__ cursor, int* __restrict__ ssrc,
                               int* __restrict__ sdst) {
    int e = blockIdx.x * 256 + threadIdx.x;
    if (e < EE) {
        int d = dst[e];
        int p = atomicAdd(&cursor[d], 1);
        ssrc[p] = src[e];
        sdst[p] = d;
    }
}

// ---------------- edge weights (SoA): one thread per CSR slot ----------------

__global__ __launch_bounds__(256) void edgew_kernel(const int* __restrict__ ssrc,
                                                    const int* __restrict__ sdst,
                                                    const float* __restrict__ el,
                                                    const float* __restrict__ er,
                                                    float* __restrict__ wgt0,
                                                    float* __restrict__ wgt1,
                                                    float* __restrict__ wgt2) {
    int p = blockIdx.x * 256 + threadIdx.x;
    if (p >= EE) return;
    int s = ssrc[p], d = sdst[p];
    float a0 = el[s * 3 + 0] + er[d * 3 + 0]; a0 = a0 > 0.f ? a0 : NEG * a0;
    float a1 = el[s * 3 + 1] + er[d * 3 + 1]; a1 = a1 > 0.f ? a1 : NEG * a1;
    float a2 = el[s * 3 + 2] + er[d * 3 + 2]; a2 = a2 > 0.f ? a2 : NEG * a2;
    wgt0[p] = __expf(a0);
    wgt1[p] = __expf(a1);
    wgt2[p] = __expf(a2);
}

// ---------------- tiled fp32 GEMM: 64x64 tile, BK=32, 4x4/thread ----------------

template <int K, int N, bool BIAS, bool RELU, bool ELER, bool A_BF16, bool C_BF16>
__global__ __launch_bounds__(256) void gemm64_kernel(const void* __restrict__ Av,
                                                     const float* __restrict__ B,
                                                     const float* __restrict__ bias,
                                                     void* __restrict__ Cv,
                                                     const float* __restrict__ al,
                                                     const float* __restrict__ ar,
                                                     float* __restrict__ el,
                                                     float* __restrict__ er) {
    __shared__ float As[32][64];   // [k][m] (transposed)
    __shared__ float Bs[32][64];   // [k][n]
    const int m0 = blockIdx.x * 64;
    const int n0 = blockIdx.y * 64;
    const int t  = threadIdx.x;
    const int tr = t >> 4;
    const int tc = t & 15;

    float acc[4][4] = {};

    for (int kt = 0; kt < K; kt += 32) {
        if (A_BF16) {
            const ushort_t* A = (const ushort_t*)Av;
            int row = t >> 2, c8 = (t & 3) * 8;
            int gr = m0 + row;
            if (gr < NN) {
                uint4 v = *(const uint4*)(A + (size_t)gr * K + kt + c8);
                As[c8 + 0][row] = bf2f((ushort_t)(v.x & 0xffff));
                As[c8 + 1][row] = bf2f((ushort_t)(v.x >> 16));
                As[c8 + 2][row] = bf2f((ushort_t)(v.y & 0xffff));
                As[c8 + 3][row] = bf2f((ushort_t)(v.y >> 16));
                As[c8 + 4][row] = bf2f((ushort_t)(v.z & 0xffff));
                As[c8 + 5][row] = bf2f((ushort_t)(v.z >> 16));
                As[c8 + 6][row] = bf2f((ushort_t)(v.w & 0xffff));
                As[c8 + 7][row] = bf2f((ushort_t)(v.w >> 16));
            } else {
#pragma unroll
                for (int j = 0; j < 8; ++j) As[c8 + j][row] = 0.f;
            }
        } else {
            const float* A = (const float*)Av;
            int f = t;
#pragma unroll
            for (int it = 0; it < 2; ++it, f += 256) {
                int row = f >> 3, c4 = (f & 7) * 4;
                float4 v = make_float4(0.f, 0.f, 0.f, 0.f);
                int gr = m0 + row;
                if (gr < NN) v = *(const float4*)(A + (size_t)gr * K + kt + c4);
                As[c4 + 0][row] = v.x;
                As[c4 + 1][row] = v.y;
                As[c4 + 2][row] = v.z;
                As[c4 + 3][row] = v.w;
            }
        }
        {
            int f = t;
#pragma unroll
            for (int it = 0; it < 2; ++it, f += 256) {
                int row = f >> 4, c4 = (f & 15) * 4;
                *(float4*)&Bs[row][c4] = *(const float4*)(B + (size_t)(kt + row) * N + n0 + c4);
            }
        }
        __syncthreads();
#pragma unroll
        for (int k = 0; k < 32; ++k) {
            float4 a = *(const float4*)&As[k][tr * 4];
            float4 b = *(const float4*)&Bs[k][tc * 4];
            acc[0][0] += a.x * b.x; acc[0][1] += a.x * b.y; acc[0][2] += a.x * b.z; acc[0][3] += a.x * b.w;
            acc[1][0] += a.y * b.x; acc[1][1] += a.y * b.y; acc[1][2] += a.y * b.z; acc[1][3] += a.y * b.w;
            acc[2][0] += a.z * b.x; acc[2][1] += a.z * b.y; acc[2][2] += a.z * b.z; acc[2][3] += a.z * b.w;
            acc[3][0] += a.w * b.x; acc[3][1] += a.w * b.y; acc[3][2] += a.w * b.z; acc[3][3] += a.w * b.w;
        }
        __syncthreads();
    }

    float4 bv = make_float4(0.f, 0.f, 0.f, 0.f);
    if (BIAS) bv = *(const float4*)(bias + n0 + tc * 4);
#pragma unroll
    for (int i = 0; i < 4; ++i) {
        int row = m0 + tr * 4 + i;
        if (row >= NN) continue;
        float4 r;
        r.x = acc[i][0]; r.y = acc[i][1]; r.z = acc[i][2]; r.w = acc[i][3];
        if (BIAS) { r.x += bv.x; r.y += bv.y; r.z += bv.z; r.w += bv.w; }
        if (RELU) {
            r.x = fmaxf(r.x, 0.f); r.y = fmaxf(r.y, 0.f);
            r.z = fmaxf(r.z, 0.f); r.w = fmaxf(r.w, 0.f);
        }
        if (C_BF16) {
            ushort4 u;
            u.x = f2bf(r.x); u.y = f2bf(r.y); u.z = f2bf(r.z); u.w = f2bf(r.w);
            *(ushort4*)((ushort_t*)Cv + (size_t)row * N + n0 + tc * 4) = u;
        } else {
            *(float4*)((float*)Cv + (size_t)row * N + n0 + tc * 4) = r;
        }
    }

    if (ELER) {
        const int h = blockIdx.y;
        float4 va = *(const float4*)(al + h * HIDF + tc * 4);
        float4 vb = *(const float4*)(ar + h * HIDF + tc * 4);
#pragma unroll
        for (int i = 0; i < 4; ++i) {
            float pl = acc[i][0] * va.x + acc[i][1] * va.y + acc[i][2] * va.z + acc[i][3] * va.w;
            float pr = acc[i][0] * vb.x + acc[i][1] * vb.y + acc[i][2] * vb.z + acc[i][3] * vb.w;
#pragma unroll
            for (int o = 1; o < 16; o <<= 1) {
                pl += __shfl_xor(pl, o, 16);
                pr += __shfl_xor(pr, o, 16);
            }
            int row = m0 + tr * 4 + i;
            if (tc == 0 && row < NN) {
                el[row * NH + h] = pl;
                er[row * NH + h] = pr;
            }
        }
    }
}

// ---------------- small GEMM for the 64->16 head (fp32) ----------------

template <int K, int M, int ROWS, bool BIAS, bool RELU>
__global__ void rowgemm_kernel(const float* __restrict__ A, const float* __restrict__ W,
                               const float* __restrict__ bias, float* __restrict__ C) {
    __shared__ float a[ROWS][K];
    const int BT = M * ROWS;
    int r0 = blockIdx.x * ROWS;
    for (int i = threadIdx.x; i < ROWS * K; i += BT) {
        int rr = i / K, kk = i - rr * K;
        int row = r0 + rr;
        a[rr][kk] = (row < NN) ? A[(size_t)row * K + kk] : 0.f;
    }
    __syncthreads();
    int rr = threadIdx.x / M, c = threadIdx.x - rr * M;
    int row = r0 + rr;
    if (row >= NN) return;
    float acc = 0.f;
#pragma unroll
    for (int k = 0; k < K; ++k) acc += a[rr][k] * W[k * M + c];
    if (BIAS) acc += bias[c];
    if (RELU) acc = fmaxf(acc, 0.f);
    C[(size_t)row * M + c] = acc;
}

// ---------------- aggregation: one wave per dst node ----------------
// lane i preloads edge (c+i)'s src index + 3 weights (coalesced); inner loop
// broadcasts them via shfl (register traffic, no memory dependency) so the
// 3 bf16 feature gathers pipeline freely across iterations.

__global__ __launch_bounds__(256) void aggregate_kernel(
    const int* __restrict__ row_ptr, const int* __restrict__ ssrc,
    const float* __restrict__ wgt0, const float* __restrict__ wgt1,
    const float* __restrict__ wgt2,
    const ushort_t* __restrict__ featb, const float* __restrict__ bias,
    ushort_t* __restrict__ outb) {
    int w = blockIdx.x * 4 + (threadIdx.x >> 6);
    if (w >= NN) return;
    int lane = threadIdx.x & 63;
    int beg = row_ptr[w], end = row_ptr[w + 1];

    float s0 = 0.f, s1 = 0.f, s2 = 0.f;
    float acc0 = 0.f, acc1 = 0.f, acc2 = 0.f;

    for (int c = beg; c < end; c += 64) {
        int n = min(64, end - c);
        int   sv  = 0;
        float wv0 = 0.f, wv1 = 0.f, wv2 = 0.f;
        if (lane < n) {
            sv  = ssrc[c + lane];
            wv0 = wgt0[c + lane];
            wv1 = wgt1[c + lane];
            wv2 = wgt2[c + lane];
        }
        // denominators: wave-reduce the preloaded weights
        float t0 = wv0, t1 = wv1, t2 = wv2;
#pragma unroll
        for (int o = 1; o < 64; o <<= 1) {
            t0 += __shfl_xor(t0, o, 64);
            t1 += __shfl_xor(t1, o, 64);
            t2 += __shfl_xor(t2, o, 64);
        }
        s0 += t0; s1 += t1; s2 += t2;

        for (int i = 0; i < n; ++i) {
            int   s  = __shfl(sv, i, 64);
            float w0 = __shfl(wv0, i, 64);
            float w1 = __shfl(wv1, i, 64);
            float w2 = __shfl(wv2, i, 64);
            const ushort_t* fr = featb + (size_t)s * FEAT;
            acc0 += w0 * bf2f(fr[lane]);
            acc1 += w1 * bf2f(fr[64 + lane]);
            acc2 += w2 * bf2f(fr[128 + lane]);
        }
    }

    float r0, r1, r2;
    if (end > beg) { r0 = acc0 / s0; r1 = acc1 / s1; r2 = acc2 / s2; }
    else           { r0 = r1 = r2 = 0.f; }
    r0 += bias[lane]; r1 += bias[64 + lane]; r2 += bias[128 + lane];
    outb[(size_t)w * FEAT + lane]       = f2bf(fmaxf(r0, 0.f));
    outb[(size_t)w * FEAT + 64 + lane]  = f2bf(fmaxf(r1, 0.f));
    outb[(size_t)w * FEAT + 128 + lane] = f2bf(fmaxf(r2, 0.f));
}

// ---------------- launch ----------------

extern "C" void kernel_launch(void* const* d_in, const int* in_sizes, int n_in,
                              void* d_out, int out_size, void* d_ws, size_t ws_size,
                              hipStream_t stream) {
    const float* features = (const float*)d_in[0];
    const int*   src      = (const int*)d_in[1];
    const int*   dst      = (const int*)d_in[2];
    const float* W1  = (const float*)d_in[3];
    const float* al1 = (const float*)d_in[4];
    const float* ar1 = (const float*)d_in[5];
    const float* b1  = (const float*)d_in[6];
    const float* W2  = (const float*)d_in[7];
    const float* al2 = (const float*)d_in[8];
    const float* ar2 = (const float*)d_in[9];
    const float* b2  = (const float*)d_in[10];
    const float* w3  = (const float*)d_in[11];
    const float* b3  = (const float*)d_in[12];
    const float* w4  = (const float*)d_in[13];
    const float* b4  = (const float*)d_in[14];
    float* out = (float*)d_out;

    char* p = (char*)d_ws;
    ushort_t* featb = (ushort_t*)p; p += (size_t)NN * FEAT * 2;    // bf16 projected feats
    ushort_t* xb    = (ushort_t*)p; p += (size_t)NN * FEAT * 2;    // bf16 layer outputs
    float* scratch  = (float*)p;    p += (size_t)NN * HIDF * 4;    // wgt (layers) / hid (head) - disjoint use
    float* el  = (float*)p; p += (size_t)NN * NH * 4;
    float* er  = (float*)p; p += (size_t)NN * NH * 4;
    int* counts  = (int*)p;  p += (size_t)NN * 4;
    int* row_ptr = (int*)p;  p += (size_t)(NN + 4) * 4;
    int* cursor  = (int*)p;  p += (size_t)NN * 4;
    int* ssrc    = (int*)p;  p += (size_t)EE * 4;
    int* sdst    = (int*)p;  p += (size_t)EE * 4;
    int* bsum    = (int*)p;  p += 128 * 4;

    float* wgt0 = scratch;             // 3 x E floats = 19.2MB <= 25.6MB
    float* wgt1 = scratch + EE;
    float* wgt2 = scratch + 2 * (size_t)EE;
    float* hid  = scratch;             // used only after last aggregate

    const int GM = (NN + 63) / 64;   // 1563
    const int GE = (EE + 255) / 256; // 6250

    // CSR by dst
    hipMemsetAsync(counts, 0, (size_t)NN * 4, stream);
    hist_kernel<<<GE, 256, 0, stream>>>(dst, counts);
    blocksum_kernel<<<NB, 256, 0, stream>>>(counts, bsum);
    scanb_kernel<<<1, 128, 0, stream>>>(bsum);
    scanfinal_kernel<<<NB, 256, 0, stream>>>(counts, bsum, row_ptr, cursor);
    scatter_kernel<<<GE, 256, 0, stream>>>(src, dst, cursor, ssrc, sdst);

    // ---- layer 1 ----
    gemm64_kernel<INF_, FEAT, false, false, true, false, true>
        <<<dim3(GM, FEAT / 64), 256, 0, stream>>>(features, W1, nullptr, featb, al1, ar1, el, er);
    edgew_kernel<<<GE, 256, 0, stream>>>(ssrc, sdst, el, er, wgt0, wgt1, wgt2);
    aggregate_kernel<<<(NN + 3) / 4, 256, 0, stream>>>(row_ptr, ssrc, wgt0, wgt1, wgt2, featb, b1, xb);

    // ---- layer 2 ----
    gemm64_kernel<FEAT, FEAT, false, false, true, true, true>
        <<<dim3(GM, FEAT / 64), 256, 0, stream>>>(xb, W2, nullptr, featb, al2, ar2, el, er);
    edgew_kernel<<<GE, 256, 0, stream>>>(ssrc, sdst, el, er, wgt0, wgt1, wgt2);
    aggregate_kernel<<<(NN + 3) / 4, 256, 0, stream>>>(row_ptr, ssrc, wgt0, wgt1, wgt2, featb, b2, xb);

    // ---- MLP head ----
    gemm64_kernel<FEAT, HIDF, true, true, false, true, false>
        <<<dim3(GM, 1), 256, 0, stream>>>(xb, w3, b3, hid, nullptr, nullptr, nullptr, nullptr);
    rowgemm_kernel<HIDF, OUTF, 16, true, false><<<NN / 16, 256, 0, stream>>>(hid, w4, b4, out);
}